// Round 2
// baseline (144.039 us; speedup 1.0000x reference)
//
#include <hip/hip_runtime.h>

#define LDSP 136  // padded row stride (272B rows, 16B-aligned for b128)

typedef _Float16 h8 __attribute__((ext_vector_type(8)));
typedef _Float16 h4 __attribute__((ext_vector_type(4)));
typedef float    f4 __attribute__((ext_vector_type(4)));
typedef float    fx16 __attribute__((ext_vector_type(16)));

// ---- fused prep: Mt[f][e] = sum_d Wk[d][f]*Wq[d][e] (f16), ck[f] = sum_d bq[d]*Wk[d][f] ----
// softmax(QK^T) == softmax(X Mt^T X^T + 1 * (ck . X^T)) -- row-constant terms drop.
__global__ void prep(const float* __restrict__ Wq, const float* __restrict__ Wk,
                     const float* __restrict__ bq, _Float16* __restrict__ Mt,
                     float* __restrict__ ck) {
    int idx = blockIdx.x * 256 + threadIdx.x;  // 16384 entries
    int e = idx & 127, f = idx >> 7;
    float a0 = 0.f, a1 = 0.f, a2 = 0.f, a3 = 0.f;
    for (int d = 0; d < 128; d += 4) {
        a0 += Wk[(d + 0) * 128 + f] * Wq[(d + 0) * 128 + e];
        a1 += Wk[(d + 1) * 128 + f] * Wq[(d + 1) * 128 + e];
        a2 += Wk[(d + 2) * 128 + f] * Wq[(d + 2) * 128 + e];
        a3 += Wk[(d + 3) * 128 + f] * Wq[(d + 3) * 128 + e];
    }
    Mt[idx] = (_Float16)((a0 + a1) + (a2 + a3));

    if (blockIdx.x == 0 && threadIdx.x < 128) {
        int t = threadIdx.x;
        float c0 = 0.f, c1 = 0.f, c2 = 0.f, c3 = 0.f;
        for (int d = 0; d < 128; d += 4) {
            c0 += bq[d + 0] * Wk[(d + 0) * 128 + t];
            c1 += bq[d + 1] * Wk[(d + 1) * 128 + t];
            c2 += bq[d + 2] * Wk[(d + 2) * 128 + t];
            c3 += bq[d + 3] * Wk[(d + 3) * 128 + t];
        }
        ck[t] = (c0 + c1) + (c2 + c3);
    }
}

// 32x32x16 MFMA version. 8 waves; wave v owns row-half hv=v&1 (u/w rows) and
// tile-quarter t4=v>>1 (f rows of Mt, d rows of Wv, w-tile of S/O).
// X fragments for the wave's 64-row half are loaded ONCE per window in phase 1
// and reused (registers) as phase 2's A operand -- no X re-read from LDS.
__global__ __launch_bounds__(512, 2) void attn(
    const float* __restrict__ x, const _Float16* __restrict__ Mt,
    const float* __restrict__ Wv, const float* __restrict__ ck,
    const float* __restrict__ bv, float* __restrict__ out) {
    __shared__ _Float16 Xs[128 * LDSP];  // X (f16), single buffer (frags persist in regs)
    __shared__ _Float16 Ts[128 * LDSP];  // T'[w][f]; overwritten with P[w][u] after phase 2
    __shared__ _Float16 Vs[128 * LDSP];  // V transposed: Vs[d][u]
    __shared__ float2   Sm[256];         // softmax (max, sum) exchange, [uhalf][w]

    const int tid  = threadIdx.x;
    const int wv   = tid >> 6;
    const int lane = tid & 63;
    const int l32  = lane & 31;
    const int hi   = lane >> 5;
    const int hv   = wv & 1;   // row-half this wave owns (u and w rows, d-half in phase 3)
    const int t4   = wv >> 1;  // f-tile (Mt rows), d-tile (Wv rows), w-tile (S/P/O rows)

    // persistent weight fragments: A = Mt rows [t4*32,+32), B = Wv rows [t4*32,+32)
    h8 mtf[8], wvf[8];
#pragma unroll
    for (int e0 = 0; e0 < 8; ++e0) {
        mtf[e0] = *(const h8*)(Mt + (t4 * 32 + l32) * 128 + e0 * 16 + hi * 8);
        const float* wp = Wv + (t4 * 32 + l32) * 128 + e0 * 16 + hi * 8;
        f4 w0 = *(const f4*)wp;
        f4 w1 = *(const f4*)(wp + 4);
        wvf[e0] = (h8){(_Float16)w0.x, (_Float16)w0.y, (_Float16)w0.z, (_Float16)w0.w,
                       (_Float16)w1.x, (_Float16)w1.y, (_Float16)w1.z, (_Float16)w1.w};
    }
    const float bvv = bv[t4 * 32 + l32];

    const size_t base0 = (size_t)blockIdx.x * 4 * (128 * 128);

    // prefetch window 0 into registers
    f4 pf[8];
#pragma unroll
    for (int j = 0; j < 8; ++j)
        pf[j] = *(const f4*)(x + base0 + 4 * tid + 2048 * j);

    for (int it = 0; it < 4; ++it) {
        // ---- stage: convert prefetched regs -> Xs (f16) ----
#pragma unroll
        for (int j = 0; j < 8; ++j) {
            int idx = 4 * tid + 2048 * j;
            int row = idx >> 7, col = idx & 127;
            f4 f = pf[j];
            h4 h = {(_Float16)f.x, (_Float16)f.y, (_Float16)f.z, (_Float16)f.w};
            *(h4*)(&Xs[row * LDSP + col]) = h;
        }
        __syncthreads();  // B1: X ready; also fences prev window's Ts/Vs readers

        // ---- phase 1a: T'[w][f] = sum_e X[w][e] Mt[f][e] + ck[f], w in own half ----
        h8 xf0[8], xf1[8];  // X rows [hv*64,+32) / [hv*64+32,+32) -- kept for phase 2
        fx16 accT0, accT1;
        {
            f4 ckv[4];
#pragma unroll
            for (int run = 0; run < 4; ++run)
                ckv[run] = *(const f4*)(ck + t4 * 32 + run * 8 + 4 * hi);
#pragma unroll
            for (int r = 0; r < 16; ++r) accT0[r] = ckv[r >> 2][r & 3];
            accT1 = accT0;
        }
#pragma unroll
        for (int e0 = 0; e0 < 8; ++e0) {
            xf0[e0] = *(const h8*)(&Xs[(hv * 64 + l32) * LDSP + e0 * 16 + hi * 8]);
            xf1[e0] = *(const h8*)(&Xs[(hv * 64 + 32 + l32) * LDSP + e0 * 16 + hi * 8]);
            accT0 = __builtin_amdgcn_mfma_f32_32x32x16_f16(mtf[e0], xf0[e0], accT0, 0, 0, 0);
            accT1 = __builtin_amdgcn_mfma_f32_32x32x16_f16(mtf[e0], xf1[e0], accT1, 0, 0, 0);
        }
        // D: col = w-local = l32, row = f = t4*32 + (r&3)+8*(r>>2)+4*hi  ->  Ts[w][f]
#pragma unroll
        for (int run = 0; run < 4; ++run) {
            h4 h0 = {(_Float16)accT0[run * 4 + 0], (_Float16)accT0[run * 4 + 1],
                     (_Float16)accT0[run * 4 + 2], (_Float16)accT0[run * 4 + 3]};
            *(h4*)(&Ts[(hv * 64 + l32) * LDSP + t4 * 32 + run * 8 + 4 * hi]) = h0;
            h4 h1 = {(_Float16)accT1[run * 4 + 0], (_Float16)accT1[run * 4 + 1],
                     (_Float16)accT1[run * 4 + 2], (_Float16)accT1[run * 4 + 3]};
            *(h4*)(&Ts[(hv * 64 + 32 + l32) * LDSP + t4 * 32 + run * 8 + 4 * hi]) = h1;
        }

        // ---- phase 1b: V[u][d] = sum_e X[u][e] Wv[d][e] + bv[d], u in own half ----
        fx16 accV0, accV1;
#pragma unroll
        for (int r = 0; r < 16; ++r) accV0[r] = bvv;
        accV1 = accV0;
#pragma unroll
        for (int e0 = 0; e0 < 8; ++e0) {
            accV0 = __builtin_amdgcn_mfma_f32_32x32x16_f16(xf0[e0], wvf[e0], accV0, 0, 0, 0);
            accV1 = __builtin_amdgcn_mfma_f32_32x32x16_f16(xf1[e0], wvf[e0], accV1, 0, 0, 0);
        }
        // D: col = d = t4*32 + l32, row = u = utile*32 + (r&3)+8*(r>>2)+4*hi -> Vs[d][u]
#pragma unroll
        for (int run = 0; run < 4; ++run) {
            h4 g0 = {(_Float16)accV0[run * 4 + 0], (_Float16)accV0[run * 4 + 1],
                     (_Float16)accV0[run * 4 + 2], (_Float16)accV0[run * 4 + 3]};
            *(h4*)(&Vs[(t4 * 32 + l32) * LDSP + hv * 64 + run * 8 + 4 * hi]) = g0;
            h4 g1 = {(_Float16)accV1[run * 4 + 0], (_Float16)accV1[run * 4 + 1],
                     (_Float16)accV1[run * 4 + 2], (_Float16)accV1[run * 4 + 3]};
            *(h4*)(&Vs[(t4 * 32 + l32) * LDSP + hv * 64 + 32 + run * 8 + 4 * hi]) = g1;
        }
        __syncthreads();  // B2: Ts, Vs ready

        // ---- issue prefetch for next window (completes during phases 2-3) ----
        if (it < 3) {
            const float* nx = x + base0 + (size_t)(it + 1) * (128 * 128);
#pragma unroll
            for (int j = 0; j < 8; ++j)
                pf[j] = *(const f4*)(nx + 4 * tid + 2048 * j);
        }

        // ---- phase 2: S[w][u] = sum_f X[u][f] T'[w][f]; w-tile = t4, u-half = hv ----
        // A = xf (registers, no LDS!), B = T' rows [t4*32,+32)
        fx16 s0, s1;
#pragma unroll
        for (int r = 0; r < 16; ++r) s0[r] = 0.f;
        s1 = s0;
#pragma unroll
        for (int f0 = 0; f0 < 8; ++f0) {
            h8 tf = *(const h8*)(&Ts[(t4 * 32 + l32) * LDSP + f0 * 16 + hi * 8]);
            s0 = __builtin_amdgcn_mfma_f32_32x32x16_f16(xf0[f0], tf, s0, 0, 0, 0);
            s1 = __builtin_amdgcn_mfma_f32_32x32x16_f16(xf1[f0], tf, s1, 0, 0, 0);
        }
        // softmax over u for col w = t4*32+l32; this wave holds u-half hv (64 vals
        // across 2 hi-lanes x 32 regs). Local-max exp (values <= 1), then one
        // (m,s) exchange with partner wave v^1; rescale folds into normalize.
        float m = -1e30f;
#pragma unroll
        for (int r = 0; r < 16; ++r) m = fmaxf(m, fmaxf(s0[r], s1[r]));
        m = fmaxf(m, __shfl_xor(m, 32, 64));
        float ss = 0.f;
#pragma unroll
        for (int r = 0; r < 16; ++r) {
            s0[r] = __expf(s0[r] - m);
            s1[r] = __expf(s1[r] - m);
            ss += s0[r] + s1[r];
        }
        ss += __shfl_xor(ss, 32, 64);
        if (hi == 0) Sm[hv * 128 + t4 * 32 + l32] = make_float2(m, ss);
        __syncthreads();  // B3: partner's (m,s) ready; also: all T' reads done
        float2 om = Sm[(hv ^ 1) * 128 + t4 * 32 + l32];
        float M   = fmaxf(m, om.x);
        float inv = __expf(m - M) / (ss * __expf(m - M) + om.y * __expf(om.x - M));
        // P[w][u] (f16) into Ts rows [t4*32,+32), cols u in own half
#pragma unroll
        for (int run = 0; run < 4; ++run) {
            h4 p0 = {(_Float16)(s0[run * 4 + 0] * inv), (_Float16)(s0[run * 4 + 1] * inv),
                     (_Float16)(s0[run * 4 + 2] * inv), (_Float16)(s0[run * 4 + 3] * inv)};
            *(h4*)(&Ts[(t4 * 32 + l32) * LDSP + hv * 64 + run * 8 + 4 * hi]) = p0;
            h4 p1 = {(_Float16)(s1[run * 4 + 0] * inv), (_Float16)(s1[run * 4 + 1] * inv),
                     (_Float16)(s1[run * 4 + 2] * inv), (_Float16)(s1[run * 4 + 3] * inv)};
            *(h4*)(&Ts[(t4 * 32 + l32) * LDSP + hv * 64 + 32 + run * 8 + 4 * hi]) = p1;
        }
        __syncthreads();  // B4: P complete (both halves of each w-tile)

        // ---- phase 3: O[w][d] = sum_u P[w][u] V[u][d]; w-tile = t4, d-half = hv ----
        fx16 o0, o1;
#pragma unroll
        for (int r = 0; r < 16; ++r) o0[r] = 0.f;
        o1 = o0;
#pragma unroll
        for (int u0 = 0; u0 < 8; ++u0) {
            h8 pr = *(const h8*)(&Ts[(t4 * 32 + l32) * LDSP + u0 * 16 + hi * 8]);
            h8 v0 = *(const h8*)(&Vs[(hv * 64 + l32) * LDSP + u0 * 16 + hi * 8]);
            h8 v1 = *(const h8*)(&Vs[(hv * 64 + 32 + l32) * LDSP + u0 * 16 + hi * 8]);
            o0 = __builtin_amdgcn_mfma_f32_32x32x16_f16(pr, v0, o0, 0, 0, 0);
            o1 = __builtin_amdgcn_mfma_f32_32x32x16_f16(pr, v1, o1, 0, 0, 0);
        }
        // D: col = d, row = w = t4*32 + (r&3)+8*(r>>2)+4*hi; 128B runs over l32
        float* ob = out + base0 + (size_t)it * (128 * 128);
#pragma unroll
        for (int r = 0; r < 16; ++r) {
            int w = t4 * 32 + (r & 3) + 8 * (r >> 2) + 4 * hi;
            ob[(size_t)w * 128 + hv * 64 + l32]      = o0[r];
            ob[(size_t)w * 128 + hv * 64 + 32 + l32] = o1[r];
        }
    }
}

extern "C" void kernel_launch(void* const* d_in, const int* in_sizes, int n_in,
                              void* d_out, int out_size, void* d_ws, size_t ws_size,
                              hipStream_t stream) {
    const float* x  = (const float*)d_in[0];
    const float* Wq = (const float*)d_in[1];
    const float* bq = (const float*)d_in[2];
    const float* Wk = (const float*)d_in[3];
    // bk (d_in[4]) drops out of softmax entirely
    const float* Wv = (const float*)d_in[5];
    const float* bv = (const float*)d_in[6];

    _Float16* Mt  = (_Float16*)d_ws;        // 32 KiB
    float*    ckp = (float*)(Mt + 16384);   // 512 B

    prep<<<64, 256, 0, stream>>>(Wq, Wk, bq, Mt, ckp);
    attn<<<256, 512, 0, stream>>>(x, Mt, Wv, ckp, bv, (float*)d_out);
}